// Round 9
// baseline (34.031 us; speedup 1.0000x reference)
//
#include <hip/hip_runtime.h>
#include <hip/hip_bf16.h>

// y = relu(x @ W1 + b1) @ W2 + b2
// x:[B,64] f32, W1:[64,128], b1:[128], W2:[128,32], b2:[32], y:[B,32] f32
//
// R4 body (best: 24.0us) + occupancy fix: w2 fragments and both bias sets
// move from persistent VGPRs (72 regs) to per-tile VOLATILE LDS reads
// (volatile = non-hoistable, avoids R6's loop-invariant re-hoist trap).
// w1 fragments stay persistent (64 regs). Target <=170 VGPR ->
// launch_bounds(256,3) -> 3 waves/SIMD, 12 waves/CU, grid 768 blocks.
#define B_ROWS 262144
#define N_TILES (B_ROWS / 16)

typedef short short8 __attribute__((ext_vector_type(8)));
typedef float f32x4 __attribute__((ext_vector_type(4)));
struct U2x2 { uint2 a, b; };

__device__ inline short f2bf(float f) {
    __hip_bfloat16 h = __float2bfloat16(f);
    return __builtin_bit_cast(short, h);
}
__device__ inline unsigned pk2(float a, float b) {
    unsigned lo = (unsigned short)f2bf(a);
    unsigned hi = (unsigned short)f2bf(b);
    return lo | (hi << 16);
}

__global__ __launch_bounds__(256, 3) void livenet_mlp(
    const float* __restrict__ x, const float* __restrict__ W1,
    const float* __restrict__ b1, const float* __restrict__ W2,
    const float* __restrict__ b2, float* __restrict__ y) {
    __shared__ __align__(16) uint2 hbu[4 * 512];    // per-wave h staging, 16 KB
    __shared__ __align__(16) short w2t[32 * 136];   // W2^T bf16, rows padded to 136
    __shared__ __align__(16) float bls[160];        // b1 | b2 (f32)

    const int tid  = threadIdx.x;
    const int wid  = tid >> 6;
    const int lane = tid & 63;
    const int g    = lane >> 4;   // k-group 0..3
    const int q    = lane & 15;   // batch row within tile
    uint2* hb = hbu + wid * 512;
    const int key = 2 * (q & 7);  // h-staging colblock XOR key (even)

    // ---- stage W2^T (bf16, padded) + biases to LDS, once per block ----
#pragma unroll
    for (int p = 0; p < 16; ++p) {
        const int idx = p * 256 + tid;      // W2 flat [k][o], k=idx>>5, o=idx&31
        w2t[(idx & 31) * 136 + (idx >> 5)] = f2bf(W2[idx]);
    }
    if (tid < 128) bls[tid] = b1[tid];
    else if (tid < 160) bls[tid] = b2[tid - 128];
    __syncthreads();

    // ---- w1 fragments: persistent registers (global f32, L2-hot) ----
    // w1f[ks][n] elem j = bf16(W1[32ks+8g+j][16n+q])
    short8 w1f[2][8];
#pragma unroll
    for (int ks = 0; ks < 2; ++ks)
#pragma unroll
        for (int n = 0; n < 8; ++n) {
            short8 v;
#pragma unroll
            for (int j = 0; j < 8; ++j)
                v[j] = f2bf(W1[(ks * 32 + g * 8 + j) * 128 + n * 16 + q]);
            w1f[ks][n] = v;
        }

    const int gwave = blockIdx.x * 4 + wid;
    const int S     = gridDim.x * 4;
    const float* xl = x + (size_t)q * 64 + g * 8;   // lane-fixed base into x

    // volatile LDS views (per-tile, non-hoistable reads)
    const volatile f32x4*  bv  = (const volatile f32x4*)bls;     // 40 f32x4
    #define W2V(nr, off) (*(const volatile short8*)&w2t[(nr) * 136 + (off)])

    // ---- depth-2 pipeline with rotation (R4-proven) ----
    f32x4 cur0, cur1, cur2, cur3, nxt0, nxt1, nxt2, nxt3;
    {
        const f32x4* p = (const f32x4*)(xl + (size_t)gwave * 1024);
        cur0 = p[0]; cur1 = p[1]; cur2 = p[8]; cur3 = p[9];
    }

    for (int tile = gwave; tile < N_TILES; tile += S) {
        const int tn = tile + S;
        if (tn < N_TILES) {
            const f32x4* p = (const f32x4*)(xl + (size_t)tn * 1024);
            nxt0 = p[0]; nxt1 = p[1]; nxt2 = p[8]; nxt3 = p[9];
        }

        const int row0 = tile * 16;

        // ---- x B-fragments: elem j = bf16(x[row0+q][32ks+8g+j]) ----
        short8 a0, a1;
        {
            short8 v;
            v[0] = f2bf(cur0[0]); v[1] = f2bf(cur0[1]); v[2] = f2bf(cur0[2]); v[3] = f2bf(cur0[3]);
            v[4] = f2bf(cur1[0]); v[5] = f2bf(cur1[1]); v[6] = f2bf(cur1[2]); v[7] = f2bf(cur1[3]);
            a0 = v;
            v[0] = f2bf(cur2[0]); v[1] = f2bf(cur2[1]); v[2] = f2bf(cur2[2]); v[3] = f2bf(cur2[3]);
            v[4] = f2bf(cur3[0]); v[5] = f2bf(cur3[1]); v[6] = f2bf(cur3[2]); v[7] = f2bf(cur3[3]);
            a1 = v;
        }

        // ---- GEMM1 (swapped): lane reg r = h[row0+q][16n+4g+r] ----
        // bias1 C-init via per-tile volatile LDS reads (broadcast, conflict-free)
        f32x4 acc1[8];
#pragma unroll
        for (int n = 0; n < 8; ++n) {
            acc1[n] = bv[n * 4 + g];
            acc1[n] = __builtin_amdgcn_mfma_f32_16x16x32_bf16(w1f[0][n], a0, acc1[n], 0, 0, 0);
            acc1[n] = __builtin_amdgcn_mfma_f32_16x16x32_bf16(w1f[1][n], a1, acc1[n], 0, 0, 0);
        }

        // ---- ReLU + pack 4 consecutive cols -> one uint2 LDS write per n ----
#pragma unroll
        for (int n = 0; n < 8; ++n) {
            uint2 w;
            w.x = pk2(fmaxf(acc1[n][0], 0.0f), fmaxf(acc1[n][1], 0.0f));
            w.y = pk2(fmaxf(acc1[n][2], 0.0f), fmaxf(acc1[n][3], 0.0f));
            hb[q * 32 + ((4 * n + g) ^ key)] = w;
        }

        // ---- read h B-frags (uint2-typed, same-wave; compiler waits) ----
        short8 ha[4];
#pragma unroll
        for (int ks = 0; ks < 4; ++ks) {
            const int jj = q * 32 + ((8 * ks + 2 * g) ^ key);
            U2x2 t{hb[jj], hb[jj + 1]};
            ha[ks] = __builtin_bit_cast(short8, t);
        }

        // ---- GEMM2 (swapped): w2 frags + bias2 via per-tile volatile LDS ----
        // w2 frag (ks,n): shorts at row (n*16+q), col ks*32+g*8 (row pad 136
        // -> 272B stride -> bank shift 4/row: worst 2-way alias = free)
        f32x4 acc2[2];
#pragma unroll
        for (int n = 0; n < 2; ++n) {
            acc2[n] = bv[32 + n * 4 + g];
#pragma unroll
            for (int ks = 0; ks < 4; ++ks) {
                short8 w = W2V(n * 16 + q, ks * 32 + g * 8);
                acc2[n] = __builtin_amdgcn_mfma_f32_16x16x32_bf16(w, ha[ks], acc2[n], 0, 0, 0);
            }
        }

        // ---- store y: two dwordx4 per lane, coalesced, nontemporal ----
#pragma unroll
        for (int n = 0; n < 2; ++n)
            __builtin_nontemporal_store(
                acc2[n], (f32x4*)(y + (size_t)(row0 + q) * 32 + n * 16 + 4 * g));

        // ---- rotate pipeline ----
        cur0 = nxt0; cur1 = nxt1; cur2 = nxt2; cur3 = nxt3;
    }
    #undef W2V
}

extern "C" void kernel_launch(void* const* d_in, const int* in_sizes, int n_in,
                              void* d_out, int out_size, void* d_ws, size_t ws_size,
                              hipStream_t stream) {
    const float* x  = (const float*)d_in[0];
    const float* W1 = (const float*)d_in[1];
    const float* b1 = (const float*)d_in[2];
    const float* W2 = (const float*)d_in[3];
    const float* b2 = (const float*)d_in[4];
    float* y = (float*)d_out;

    // 768 blocks x 4 waves: 3 blocks/CU (VGPR<=170 via launch_bounds(256,3),
    // LDS 25.7KB) -> 12 waves/CU, +50% concurrent load streams vs R4.
    const int blocks = 768;
    livenet_mlp<<<blocks, 256, 0, stream>>>(x, W1, b1, W2, b2, y);
}

// Round 10
// 24.466 us; speedup vs baseline: 1.3910x; 1.3910x over previous
//
#include <hip/hip_runtime.h>
#include <hip/hip_bf16.h>

// y = relu(x @ W1 + b1) @ W2 + b2
// x:[B,64] f32, W1:[64,128], b1:[128], W2:[128,32], b2:[32], y:[B,32] f32
//
// LDS-FREE structure. Swapped-operand MFMAs (lane holds batch row q).
// GEMM1's h-column-to-tile assignment is permuted by the bijection
//   pi(n, m) = 32*(n&3) + 8*(m>>2) + 4*(n>>2) + (m&3)   (m = 4g+r)
// so that each lane's GEMM1 outputs are exactly the h-values its own
// GEMM2 B-fragments need: ha[ks][j] = relu(acc1[ks+4*(j>>2)][j&3]).
// The h LDS round-trip (8 ds_write + 4 ds_read + lgkmcnt waits + barrier)
// vanishes; kernel uses zero LDS. W1 frags gather pi-permuted columns and
// b1 is pi-permuted (consecutive f32x4 stays consecutive); W2/x/y layouts
// unchanged, per-output accumulation order unchanged -> bit-identical result.
#define B_ROWS 262144
#define N_TILES (B_ROWS / 16)

typedef short short8 __attribute__((ext_vector_type(8)));
typedef float f32x4 __attribute__((ext_vector_type(4)));

__device__ inline short f2bf(float f) {
    __hip_bfloat16 h = __float2bfloat16(f);
    return __builtin_bit_cast(short, h);
}

__global__ __launch_bounds__(256, 2) void livenet_mlp(
    const float* __restrict__ x, const float* __restrict__ W1,
    const float* __restrict__ b1, const float* __restrict__ W2,
    const float* __restrict__ b2, float* __restrict__ y) {
    const int tid  = threadIdx.x;
    const int wid  = tid >> 6;
    const int lane = tid & 63;
    const int g    = lane >> 4;   // k-group 0..3
    const int q    = lane & 15;   // batch row within tile

    // ---- weight fragments, once per wave (global, L2/L3-hot) ----
    // w1f[ks][n] elem j = bf16(W1[32ks+8g+j][pi(n,q)])
    //   pi(n,q) = 32*(n&3) + 8*(q>>2) + 4*(n>>2) + (q&3)
    short8 w1f[2][8];
#pragma unroll
    for (int ks = 0; ks < 2; ++ks)
#pragma unroll
        for (int n = 0; n < 8; ++n) {
            const int pc = 32 * (n & 3) + 8 * (q >> 2) + 4 * (n >> 2) + (q & 3);
            short8 v;
#pragma unroll
            for (int j = 0; j < 8; ++j)
                v[j] = f2bf(W1[(ks * 32 + g * 8 + j) * 128 + pc]);
            w1f[ks][n] = v;
        }
    // w2f[ks][n] elem j = bf16(W2[32ks+8g+j][16n+q])  (unchanged layout)
    short8 w2f[4][2];
#pragma unroll
    for (int ks = 0; ks < 4; ++ks)
#pragma unroll
        for (int n = 0; n < 2; ++n) {
            short8 v;
#pragma unroll
            for (int j = 0; j < 8; ++j)
                v[j] = f2bf(W2[(ks * 32 + g * 8 + j) * 32 + n * 16 + q]);
            w2f[ks][n] = v;
        }
    // bias C-init: binit1[n] reg r = b1[pi(n,4g+r)] -> consecutive f32x4
    f32x4 binit1[8], binit2[2];
#pragma unroll
    for (int n = 0; n < 8; ++n)
        binit1[n] = *(const f32x4*)(b1 + 32 * (n & 3) + 8 * g + 4 * (n >> 2));
#pragma unroll
    for (int n = 0; n < 2; ++n)
        binit2[n] = *(const f32x4*)(b2 + n * 16 + 4 * g);

    const int gwave = blockIdx.x * 4 + wid;
    const int S     = gridDim.x * 4;
    const float* xl = x + (size_t)q * 64 + g * 8;  // lane-fixed base into x

    // ---- depth-1 pipeline with rotation (R4-proven best) ----
    f32x4 cur0, cur1, cur2, cur3, nxt0, nxt1, nxt2, nxt3;
    {
        const f32x4* p = (const f32x4*)(xl + (size_t)gwave * 1024);
        cur0 = p[0]; cur1 = p[1]; cur2 = p[8]; cur3 = p[9];
    }

    for (int tile = gwave; tile < N_TILES; tile += S) {
        const int tn = tile + S;
        if (tn < N_TILES) {
            const f32x4* p = (const f32x4*)(xl + (size_t)tn * 1024);
            nxt0 = p[0]; nxt1 = p[1]; nxt2 = p[8]; nxt3 = p[9];
        }

        const int row0 = tile * 16;

        // ---- x B-fragments: elem j = bf16(x[row0+q][32ks+8g+j]) ----
        short8 a0, a1;
        {
            short8 v;
            v[0] = f2bf(cur0[0]); v[1] = f2bf(cur0[1]); v[2] = f2bf(cur0[2]); v[3] = f2bf(cur0[3]);
            v[4] = f2bf(cur1[0]); v[5] = f2bf(cur1[1]); v[6] = f2bf(cur1[2]); v[7] = f2bf(cur1[3]);
            a0 = v;
            v[0] = f2bf(cur2[0]); v[1] = f2bf(cur2[1]); v[2] = f2bf(cur2[2]); v[3] = f2bf(cur2[3]);
            v[4] = f2bf(cur3[0]); v[5] = f2bf(cur3[1]); v[6] = f2bf(cur3[2]); v[7] = f2bf(cur3[3]);
            a1 = v;
        }

        // ---- GEMM1 (swapped, pi-permuted): lane reg r = h[row0+q][pi(n,4g+r)]
        f32x4 acc1[8];
#pragma unroll
        for (int n = 0; n < 8; ++n) {
            acc1[n] = __builtin_amdgcn_mfma_f32_16x16x32_bf16(w1f[0][n], a0, binit1[n], 0, 0, 0);
            acc1[n] = __builtin_amdgcn_mfma_f32_16x16x32_bf16(w1f[1][n], a1, acc1[n], 0, 0, 0);
        }

        // ---- in-register h repack: ha[ks][j] = relu(acc1[ks+4*(j>>2)][j&3])
        // (pi makes each lane's needed B-frag values lane-local; no LDS)
        short8 ha[4];
#pragma unroll
        for (int ks = 0; ks < 4; ++ks) {
            short8 v;
            v[0] = f2bf(fmaxf(acc1[ks][0], 0.0f));
            v[1] = f2bf(fmaxf(acc1[ks][1], 0.0f));
            v[2] = f2bf(fmaxf(acc1[ks][2], 0.0f));
            v[3] = f2bf(fmaxf(acc1[ks][3], 0.0f));
            v[4] = f2bf(fmaxf(acc1[ks + 4][0], 0.0f));
            v[5] = f2bf(fmaxf(acc1[ks + 4][1], 0.0f));
            v[6] = f2bf(fmaxf(acc1[ks + 4][2], 0.0f));
            v[7] = f2bf(fmaxf(acc1[ks + 4][3], 0.0f));
            ha[ks] = v;
        }

        // ---- GEMM2 (swapped): lane reg r = y[row0+q][16n+4g+r] ----
        f32x4 acc2[2];
#pragma unroll
        for (int n = 0; n < 2; ++n) {
            acc2[n] = __builtin_amdgcn_mfma_f32_16x16x32_bf16(w2f[0][n], ha[0], binit2[n], 0, 0, 0);
#pragma unroll
            for (int ks = 1; ks < 4; ++ks)
                acc2[n] = __builtin_amdgcn_mfma_f32_16x16x32_bf16(w2f[ks][n], ha[ks], acc2[n], 0, 0, 0);
        }

        // ---- store y: two dwordx4 per lane, coalesced, nontemporal ----
#pragma unroll
        for (int n = 0; n < 2; ++n)
            __builtin_nontemporal_store(
                acc2[n], (f32x4*)(y + (size_t)(row0 + q) * 32 + n * 16 + 4 * g));

        // ---- rotate pipeline ----
        cur0 = nxt0; cur1 = nxt1; cur2 = nxt2; cur3 = nxt3;
    }
}

extern "C" void kernel_launch(void* const* d_in, const int* in_sizes, int n_in,
                              void* d_out, int out_size, void* d_ws, size_t ws_size,
                              hipStream_t stream) {
    const float* x  = (const float*)d_in[0];
    const float* W1 = (const float*)d_in[1];
    const float* b1 = (const float*)d_in[2];
    const float* W2 = (const float*)d_in[3];
    const float* b2 = (const float*)d_in[4];
    float* y = (float*)d_out;

    // 512 blocks x 4 waves = 2048 waves (8 waves/CU at 2/SIMD); 8 tiles/wave.
    const int blocks = 512;
    livenet_mlp<<<blocks, 256, 0, stream>>>(x, W1, b1, W2, b2, y);
}

// Round 11
// 24.317 us; speedup vs baseline: 1.3995x; 1.0061x over previous
//
#include <hip/hip_runtime.h>
#include <hip/hip_bf16.h>

// y = relu(x @ W1 + b1) @ W2 + b2
// x:[B,64] f32, W1:[64,128], b1:[128], W2:[128,32], b2:[32], y:[B,32] f32
//
// R10 body (LDS-free pi-permuted MFMA structure, depth-1 pipeline, NT stores)
// + H1 fix: the per-wave scattered global weight GATHER prologue (~192
// 64-lane line-sprayed loads per wave) is replaced by block-coalesced
// staging of W1/W2 into LDS (bf16, transposed, c16 XOR-swizzled) and
// once-per-wave b128 LDS frag reads. Body/registers/occupancy unchanged.
#define B_ROWS 262144
#define N_TILES (B_ROWS / 16)

typedef short short8 __attribute__((ext_vector_type(8)));
typedef float f32x4 __attribute__((ext_vector_type(4)));

__device__ inline short f2bf(float f) {
    __hip_bfloat16 h = __float2bfloat16(f);
    return __builtin_bit_cast(short, h);
}

__global__ __launch_bounds__(256, 2) void livenet_mlp(
    const float* __restrict__ x, const float* __restrict__ W1,
    const float* __restrict__ b1, const float* __restrict__ W2,
    const float* __restrict__ b2, float* __restrict__ y) {
    // W1^T / W2^T in LDS, bf16, 16B-block swizzled:
    //  W1 elem [r][c] at short idx  c*64 + ((r>>3) ^ (c&7))*8      + (r&7)
    //  W2 elem [r][c] at short idx  c*128 + ((r>>3) ^ (2*(c&7)))*8 + (r&7)
    __shared__ __align__(16) short w1s[128 * 64];   // 16 KB
    __shared__ __align__(16) short w2s[32 * 128];   // 8 KB

    const int tid  = threadIdx.x;
    const int wid  = tid >> 6;
    const int lane = tid & 63;
    const int g    = lane >> 4;   // k-group 0..3
    const int q    = lane & 15;   // batch row within tile

    // ---- coalesced staging: global f32 -> LDS bf16^T (once per block) ----
#pragma unroll
    for (int p = 0; p < 8; ++p) {              // W1: 8192 elems
        const int idx = p * 1024 + tid * 4;
        f32x4 v = *(const f32x4*)(W1 + idx);
        const int r = idx >> 7, c = idx & 127;
#pragma unroll
        for (int e = 0; e < 4; ++e) {
            const int ce = c + e;
            w1s[ce * 64 + (((r >> 3) ^ (ce & 7)) * 8) + (r & 7)] = f2bf(v[e]);
        }
    }
#pragma unroll
    for (int p = 0; p < 4; ++p) {              // W2: 4096 elems
        const int idx = p * 1024 + tid * 4;
        f32x4 v = *(const f32x4*)(W2 + idx);
        const int r = idx >> 5, c = idx & 31;
#pragma unroll
        for (int e = 0; e < 4; ++e) {
            const int ce = c + e;
            w2s[ce * 128 + (((r >> 3) ^ (2 * (ce & 7))) * 8) + (r & 7)] = f2bf(v[e]);
        }
    }
    __syncthreads();

    // ---- weight fragments: LDS -> registers, ONCE per wave ----
    // w1f[ks][n] elem j = bf16(W1[32ks+8g+j][pi(n,q)]),
    //   pi(n,q) = 32*(n&3) + 8*(q>>2) + 4*(n>>2) + (q&3)
    short8 w1f[2][8];
#pragma unroll
    for (int ks = 0; ks < 2; ++ks)
#pragma unroll
        for (int n = 0; n < 8; ++n) {
            const int pc = 32 * (n & 3) + 8 * (q >> 2) + 4 * (n >> 2) + (q & 3);
            w1f[ks][n] = *(const short8*)&w1s[pc * 64 + ((4 * ks + g) ^ (pc & 7)) * 8];
        }
    // w2f[ks][n] elem j = bf16(W2[32ks+8g+j][16n+q])
    short8 w2f[4][2];
#pragma unroll
    for (int ks = 0; ks < 4; ++ks)
#pragma unroll
        for (int n = 0; n < 2; ++n) {
            const int c = n * 16 + q;
            w2f[ks][n] = *(const short8*)&w2s[c * 128 + ((4 * ks + g) ^ (2 * (q & 7))) * 8];
        }
    // bias C-init from global (L2-hot, R10-proven): reg r = b1[pi(n,4g+r)]
    f32x4 binit1[8], binit2[2];
#pragma unroll
    for (int n = 0; n < 8; ++n)
        binit1[n] = *(const f32x4*)(b1 + 32 * (n & 3) + 8 * g + 4 * (n >> 2));
#pragma unroll
    for (int n = 0; n < 2; ++n)
        binit2[n] = *(const f32x4*)(b2 + n * 16 + 4 * g);

    const int gwave = blockIdx.x * 4 + wid;
    const int S     = gridDim.x * 4;
    const float* xl = x + (size_t)q * 64 + g * 8;  // lane-fixed base into x

    // ---- depth-1 pipeline with rotation (R4/R10-proven) ----
    f32x4 cur0, cur1, cur2, cur3, nxt0, nxt1, nxt2, nxt3;
    {
        const f32x4* p = (const f32x4*)(xl + (size_t)gwave * 1024);
        cur0 = p[0]; cur1 = p[1]; cur2 = p[8]; cur3 = p[9];
    }

    for (int tile = gwave; tile < N_TILES; tile += S) {
        const int tn = tile + S;
        if (tn < N_TILES) {
            const f32x4* p = (const f32x4*)(xl + (size_t)tn * 1024);
            nxt0 = p[0]; nxt1 = p[1]; nxt2 = p[8]; nxt3 = p[9];
        }

        const int row0 = tile * 16;

        // ---- x B-fragments: elem j = bf16(x[row0+q][32ks+8g+j]) ----
        short8 a0, a1;
        {
            short8 v;
            v[0] = f2bf(cur0[0]); v[1] = f2bf(cur0[1]); v[2] = f2bf(cur0[2]); v[3] = f2bf(cur0[3]);
            v[4] = f2bf(cur1[0]); v[5] = f2bf(cur1[1]); v[6] = f2bf(cur1[2]); v[7] = f2bf(cur1[3]);
            a0 = v;
            v[0] = f2bf(cur2[0]); v[1] = f2bf(cur2[1]); v[2] = f2bf(cur2[2]); v[3] = f2bf(cur2[3]);
            v[4] = f2bf(cur3[0]); v[5] = f2bf(cur3[1]); v[6] = f2bf(cur3[2]); v[7] = f2bf(cur3[3]);
            a1 = v;
        }

        // ---- GEMM1 (swapped, pi-permuted): lane reg r = h[row0+q][pi(n,4g+r)]
        f32x4 acc1[8];
#pragma unroll
        for (int n = 0; n < 8; ++n) {
            acc1[n] = __builtin_amdgcn_mfma_f32_16x16x32_bf16(w1f[0][n], a0, binit1[n], 0, 0, 0);
            acc1[n] = __builtin_amdgcn_mfma_f32_16x16x32_bf16(w1f[1][n], a1, acc1[n], 0, 0, 0);
        }

        // ---- in-register h repack: ha[ks][j] = relu(acc1[ks+4*(j>>2)][j&3])
        short8 ha[4];
#pragma unroll
        for (int ks = 0; ks < 4; ++ks) {
            short8 v;
            v[0] = f2bf(fmaxf(acc1[ks][0], 0.0f));
            v[1] = f2bf(fmaxf(acc1[ks][1], 0.0f));
            v[2] = f2bf(fmaxf(acc1[ks][2], 0.0f));
            v[3] = f2bf(fmaxf(acc1[ks][3], 0.0f));
            v[4] = f2bf(fmaxf(acc1[ks + 4][0], 0.0f));
            v[5] = f2bf(fmaxf(acc1[ks + 4][1], 0.0f));
            v[6] = f2bf(fmaxf(acc1[ks + 4][2], 0.0f));
            v[7] = f2bf(fmaxf(acc1[ks + 4][3], 0.0f));
            ha[ks] = v;
        }

        // ---- GEMM2 (swapped): lane reg r = y[row0+q][16n+4g+r] ----
        f32x4 acc2[2];
#pragma unroll
        for (int n = 0; n < 2; ++n) {
            acc2[n] = __builtin_amdgcn_mfma_f32_16x16x32_bf16(w2f[0][n], ha[0], binit2[n], 0, 0, 0);
#pragma unroll
            for (int ks = 1; ks < 4; ++ks)
                acc2[n] = __builtin_amdgcn_mfma_f32_16x16x32_bf16(w2f[ks][n], ha[ks], acc2[n], 0, 0, 0);
        }

        // ---- store y: two dwordx4 per lane, coalesced, nontemporal ----
#pragma unroll
        for (int n = 0; n < 2; ++n)
            __builtin_nontemporal_store(
                acc2[n], (f32x4*)(y + (size_t)(row0 + q) * 32 + n * 16 + 4 * g));

        // ---- rotate pipeline ----
        cur0 = nxt0; cur1 = nxt1; cur2 = nxt2; cur3 = nxt3;
    }
}

extern "C" void kernel_launch(void* const* d_in, const int* in_sizes, int n_in,
                              void* d_out, int out_size, void* d_ws, size_t ws_size,
                              hipStream_t stream) {
    const float* x  = (const float*)d_in[0];
    const float* W1 = (const float*)d_in[1];
    const float* b1 = (const float*)d_in[2];
    const float* W2 = (const float*)d_in[3];
    const float* b2 = (const float*)d_in[4];
    float* y = (float*)d_out;

    // 512 blocks x 4 waves = 2048 waves (2 blocks/CU, 8 waves/CU); 8 tiles/wave.
    const int blocks = 512;
    livenet_mlp<<<blocks, 256, 0, stream>>>(x, W1, b1, W2, b2, y);
}